// Round 1
// 1136.542 us; speedup vs baseline: 1.2112x; 1.2112x over previous
//
#include <hip/hip_runtime.h>
#include <stdint.h>

#define TOKENS 8192
#define IN_F   4096
#define OUT_F  11008
#define PACKED (OUT_F / 2)
#define NKT    (IN_F / 64)   // 64 K-tiles of BK=64

typedef __bf16   bf16x8 __attribute__((ext_vector_type(8)));
typedef float    f32x4  __attribute__((ext_vector_type(4)));
typedef uint16_t u16x8  __attribute__((ext_vector_type(8)));

__device__ __forceinline__ uint16_t f32_to_bf16(float f) {
    union { float f; uint32_t u; } c; c.f = f;
    uint32_t r = c.u + 0x7FFFu + ((c.u >> 16) & 1u);
    return (uint16_t)(r >> 16);
}

// ---------------- kernel 1: x fp32 -> bf16 (unchanged) ----------------
__global__ __launch_bounds__(256) void xcvt_kernel(const float* __restrict__ x,
                                                   uint16_t* __restrict__ xb) {
    size_t base = ((size_t)blockIdx.x * 256 + threadIdx.x) * 8;
    float4 v0 = *(const float4*)(x + base);
    float4 v1 = *(const float4*)(x + base + 4);
    u16x8 o;
    o[0] = f32_to_bf16(v0.x); o[1] = f32_to_bf16(v0.y);
    o[2] = f32_to_bf16(v0.z); o[3] = f32_to_bf16(v0.w);
    o[4] = f32_to_bf16(v1.x); o[5] = f32_to_bf16(v1.y);
    o[6] = f32_to_bf16(v1.z); o[7] = f32_to_bf16(v1.w);
    *(u16x8*)(xb + base) = o;
}

// ------- kernel 2: unpack int4 -> bf16 W^T [OUT_F][IN_F] (unchanged) -------
#define WDQ_STRIDE 72
__global__ __launch_bounds__(256) void wdeq_kernel(const int* __restrict__ wp,
                                                   const float* __restrict__ woff,
                                                   uint16_t* __restrict__ wt) {
    __shared__ uint16_t tile[64 * WDQ_STRIDE];
    const int t  = threadIdx.x;
    const int p0 = blockIdx.y * 32;
    const int k0 = blockIdx.x * 64;
    const int pl = t & 31;
    const int kb = t >> 5;
    const int p  = p0 + pl;
    const float off_e = woff[2 * p];
    const float off_o = woff[2 * p + 1];
    #pragma unroll
    for (int j = 0; j < 8; ++j) {
        int kl = j * 8 + kb;
        int v  = wp[(size_t)(k0 + kl) * PACKED + p];
        int lo = ((v & 15) ^ 8) - 8;
        int hi = (((v >> 4) & 15) ^ 8) - 8;
        tile[(2 * pl)     * WDQ_STRIDE + kl] = f32_to_bf16((float)lo + off_e);
        tile[(2 * pl + 1) * WDQ_STRIDE + kl] = f32_to_bf16((float)hi + off_o);
    }
    __syncthreads();
    const int nl = t >> 2;
    const int kc = (t & 3) * 16;
    u16x8 w0 = *(const u16x8*)&tile[nl * WDQ_STRIDE + kc];
    u16x8 w1 = *(const u16x8*)&tile[nl * WDQ_STRIDE + kc + 8];
    uint16_t* dst = wt + (size_t)(2 * p0 + nl) * IN_F + k0 + kc;
    *(u16x8*)dst       = w0;
    *(u16x8*)(dst + 8) = w1;
}

// ---------------- kernel 3: 256x256 8-phase bf16 GEMM (m201-style) ----------------
// A = xb [M,K] rm, B^T = wt [N,K] rm, out [M,N] fp32; epilogue out = acc*scale[n]+bias[n].
// 8 waves (2Mx4N), BK=64, LDS 128 KiB = 2dbuf x 2half x [128][64] x {A,B}.
// Per K-tile 4 phases: {ds_read subtile | stage 1 half-tile | bar | setprio;16 MFMA; | bar}.
// Counted vmcnt(4) once per K-tile (phase 4) -> loads live across barriers (T4).
// Swizzle: LDS linear; chunk (16B) stored at pos c^(row&7); staging pre-swizzles the
// GLOBAL source (rule 21), ds_read applies same XOR. row&7 == l15&7 for all fragments.
//
// Stage stream ledger (verified by hand):
//   during kt: P1 A0(kt+1), P2 A1(kt+1), P3 B0(kt+2), P4 B1(kt+2); 2 loads each.
//   entering kt: [B0(kt+1),B1(kt+1)] outstanding (4). After P4 issue: 12.
//   vmcnt(4) at P4 retires through A1(kt+1) -> kt+1 fully landed; leaves B(kt+2) pair.
//   WAR: A slots (parity p^1) untouched by current reads; B0 slot last read P2, written P3;
//   B1 slot last read P2, written P4 -> >=1 barrier between in all cases.
//   Tail: kt=62 stages A(63) only, vmcnt(0) at its P4; kt=63 stages nothing.

#define CP16(ldsp, gp)                                                                        \
    __builtin_amdgcn_global_load_lds((const __attribute__((address_space(1))) void*)(gp),     \
                                     (__attribute__((address_space(3))) void*)(ldsp), 16, 0, 0)

#define STAGE2(ldsoff, gptr) {                                      \
    CP16((char*)smem + (ldsoff),        (gptr));                    \
    CP16((char*)smem + (ldsoff) + 8192, (gptr) + 262144); }

#define FENCE() asm volatile("" ::: "memory")
#define BAR()  { FENCE(); __builtin_amdgcn_s_barrier(); FENCE(); }

#define LDA(MH) {                                                       \
    _Pragma("unroll") for (int im = 0; im < 4; ++im) {                  \
      a[im][0] = *(const bf16x8*)(Ard + ((MH)*4+im)*2048 + swz0);       \
      a[im][1] = *(const bf16x8*)(Ard + ((MH)*4+im)*2048 + swz1); } }

#define LDB(dst, NH) {                                                  \
    _Pragma("unroll") for (int i2 = 0; i2 < 2; ++i2) {                  \
      dst[i2][0] = *(const bf16x8*)(Brd + ((NH)*2+i2)*2048 + swz0);     \
      dst[i2][1] = *(const bf16x8*)(Brd + ((NH)*2+i2)*2048 + swz1); } }

#define MMA(MH, NH, B) {                                                \
    __builtin_amdgcn_s_setprio(1);                                      \
    _Pragma("unroll") for (int ik = 0; ik < 2; ++ik)                    \
      _Pragma("unroll") for (int im = 0; im < 4; ++im)                  \
        _Pragma("unroll") for (int i2 = 0; i2 < 2; ++i2)                \
          acc[(MH)*4+im][(NH)*2+i2] = __builtin_amdgcn_mfma_f32_16x16x32_bf16( \
              a[im][ik], B[i2][ik], acc[(MH)*4+im][(NH)*2+i2], 0, 0, 0); \
    __builtin_amdgcn_s_setprio(0); }

__global__ __launch_bounds__(512, 2) void gemm_kernel(const uint16_t* __restrict__ xb,
                                                      const uint16_t* __restrict__ wt,
                                                      const float* __restrict__ scale,
                                                      const float* __restrict__ bias,
                                                      float* __restrict__ out) {
    // LDS map (bytes): A: p*32768 + h*16384 + row*128 + chunkpos*16
    //                  B: 65536 + same
    __shared__ char smem[131072];

    const int tid  = threadIdx.x;
    const int w    = tid >> 6;
    const int lane = tid & 63;
    const int quad = lane >> 4;
    const int l15  = lane & 15;
    const int wm   = w >> 2;          // 0..1: wave row (128 out rows)
    const int wn   = w & 3;           // 0..3: wave col (64 out cols)

    const int bm = blockIdx.x & 31;   // M/256 = 32, m-fastest for B-panel L2/L3 reuse
    const int bn = blockIdx.x >> 5;   // 0..42
    const int m0 = bm << 8;
    const int n0 = bn << 8;

    // ---- staging addresses: thread t covers LDS o = t*16 (rows 0-63) and o+8192
    // (rows 64-127); content at o must be global chunk (o_chunk ^ row&7).
    const int srow = tid >> 3;                       // 0..63
    const int schk = (tid & 7) ^ (srow & 7);
    const uint16_t* gA = xb + (size_t)(m0 + srow) * IN_F + schk * 8;
    const uint16_t* gB = wt + (size_t)(n0 + srow) * IN_F + schk * 8;
    const int wb = w * 1024;                         // wave-uniform LDS sub-base

    // ---- fragment-read lane offsets (row&7 == l15&7; frag_m*16 preserves it)
    const int swz0 = (( quad     ) ^ (l15 & 7)) * 16 + l15 * 128;   // kk=0
    const int swz1 = ((quad + 4) ^ (l15 & 7)) * 16 + l15 * 128;     // kk=1

    const char* lds = (const char*)smem;

    // ---- prologue: stage K0 fully + B(1) pair; vmcnt(4) leaves B(1) in flight
    STAGE2(65536 +                 wb, gB);                  // B0(0)
    STAGE2(65536 + 16384 +         wb, gB + 524288);         // B1(0)
    STAGE2(                        wb, gA);                  // A0(0)
    STAGE2(16384 +                 wb, gA + 524288);         // A1(0)
    STAGE2(65536 + 32768 +         wb, gB + 64);             // B0(1)
    STAGE2(65536 + 32768 + 16384 + wb, gB + 64 + 524288);    // B1(1)
    asm volatile("s_waitcnt vmcnt(4)" ::: "memory");
    BAR();

    f32x4  acc[8][4] = {};
    bf16x8 a[4][2], b0[2][2], b1[2][2];

    #pragma unroll 2
    for (int kt = 0; kt < NKT; ++kt) {
        const int p = kt & 1;
        const char* Ard = lds + p * 32768 + wm * 16384;
        const char* Brd = lds + 65536 + p * 32768 + (wn >> 1) * 16384 + (wn & 1) * 8192;
        const int AstB = (p ^ 1) * 32768 + wb;        // A(kt+1) slots
        const int BstB = 65536 + p * 32768 + wb;      // B(kt+2) slots (same parity as cur)
        const bool stA = kt < NKT - 1;
        const bool stB = kt < NKT - 2;

        // ---- P1: Q(0,0) — read a(mh0), b0(nh0); stage A0(kt+1)
        LDA(0); LDB(b0, 0);
        if (stA) STAGE2(AstB, gA + 64);
        BAR();
        MMA(0, 0, b0);
        BAR();
        // ---- P2: Q(0,1) — read b1(nh1); stage A1(kt+1)
        LDB(b1, 1);
        if (stA) STAGE2(AstB + 16384, gA + 64 + 524288);
        BAR();
        MMA(0, 1, b1);
        BAR();
        // ---- P3: Q(1,1) — read a(mh1); stage B0(kt+2)
        LDA(1);
        if (stB) STAGE2(BstB, gB + 128);
        BAR();
        MMA(1, 1, b1);
        BAR();
        // ---- P4: Q(1,0) — regs only; stage B1(kt+2); counted vmcnt
        if (stB) STAGE2(BstB + 16384, gB + 128 + 524288);
        if (kt < NKT - 2)       { asm volatile("s_waitcnt vmcnt(4)" ::: "memory"); }
        else if (kt == NKT - 2) { asm volatile("s_waitcnt vmcnt(0)" ::: "memory"); }
        BAR();
        MMA(1, 0, b0);
        BAR();

        gA += 64; gB += 64;
    }

    // ---- epilogue: out = acc * scale[n] + bias[n]
    // C/D layout (verified m89/m91): col = lane&15, row = quad*4 + reg
    #pragma unroll
    for (int nf = 0; nf < 4; ++nf) {
        const int n    = n0 + wn * 64 + nf * 16 + l15;
        const float s  = scale[n];
        const float bb = bias[n];
        #pragma unroll
        for (int mf = 0; mf < 8; ++mf) {
            const int m = m0 + wm * 128 + mf * 16 + quad * 4;
            float* o = out + (size_t)m * OUT_F + n;
            #pragma unroll
            for (int r = 0; r < 4; ++r)
                o[(size_t)r * OUT_F] = acc[mf][nf][r] * s + bb;
        }
    }
}

extern "C" void kernel_launch(void* const* d_in, const int* in_sizes, int n_in,
                              void* d_out, int out_size, void* d_ws, size_t ws_size,
                              hipStream_t stream) {
    const float* x     = (const float*)d_in[0];
    const int*   wp    = (const int*)d_in[1];
    const float* scale = (const float*)d_in[2];
    const float* woff  = (const float*)d_in[3];
    const float* bias  = (const float*)d_in[4];
    float* out = (float*)d_out;

    uint16_t* xb = (uint16_t*)d_ws;                      // 64 MiB
    uint16_t* wt = xb + (size_t)TOKENS * IN_F;           // 86 MiB

    xcvt_kernel<<<(TOKENS * (size_t)IN_F) / (256 * 8), 256, 0, stream>>>(x, xb);
    wdeq_kernel<<<dim3(IN_F / 64, PACKED / 32), 256, 0, stream>>>(wp, woff, wt);
    gemm_kernel<<<(TOKENS / 256) * (OUT_F / 256), 512, 0, stream>>>(xb, wt, scale, bias, out);
}